// Round 1
// baseline (318.542 us; speedup 1.0000x reference)
//
#include <hip/hip_runtime.h>
#include <math.h>

#define NUM_KV_HEADS 8
#define HEAD_DIM 128
#define BLOCK_SZ 16
#define MODEL_CTX 4096
#define CHUNK 256   // tokens per split-K chunk

// Kernel 1: per-(chunk, b*h) partial attention with on-the-fly neox RoPE on K.
// Each half-wave (32 lanes) processes one token at a time:
//   lane sl holds d = {2sl, 2sl+1} (rope "x1" half) and {64+2sl, 65+2sl} ("x2" half)
// so the rotation needs no cross-lane traffic; the 128-long dot is a 5-step
// __shfl_xor reduction within the 32-lane group.
__global__ __launch_bounds__(256, 4)
void attn_partial(const float* __restrict__ q,
                  const float* __restrict__ knew,
                  const float* __restrict__ vnew,
                  const float* __restrict__ kcache,
                  const float* __restrict__ vcache,
                  const int* __restrict__ btab,
                  const int* __restrict__ seqlen_p,
                  int nbps,                      // blocks per sequence (256)
                  float* __restrict__ o_part,    // [B*H][n_chunks][128]
                  float* __restrict__ m_part,    // [B*H][n_chunks]
                  float* __restrict__ l_part,    // [B*H][n_chunks]
                  int n_chunks)
{
    const int chunk = blockIdx.x;
    const int bh    = blockIdx.y;
    const int b     = bh / NUM_KV_HEADS;
    const int h     = bh % NUM_KV_HEADS;
    const int tid   = threadIdx.x;
    const int lane  = tid & 63;
    const int wave  = tid >> 6;
    const int sl    = lane & 31;          // sub-lane within half-wave
    const int half  = lane >> 5;
    const int hw    = wave * 2 + half;    // half-wave id 0..7

    __shared__ float sc[CHUNK];           // scores, then probs
    __shared__ float red[8];              // [0..3] wave max, [4..7] wave sum
    __shared__ float po[8][HEAD_DIM];     // per-half-wave partial o

    const int seq_len = *seqlen_p;
    const int rem = (seq_len - 1) % BLOCK_SZ;
    const int T   = (nbps - 1) * BLOCK_SZ + rem + 1;   // total keys incl. new token

    // inv_freq for this lane's two frequency indices f0=2sl, f1=2sl+1
    const float lf    = -logf(10000.0f) * (2.0f / (float)HEAD_DIM);
    const float invf0 = expf(lf * (float)(2 * sl));
    const float invf1 = expf(lf * (float)(2 * sl + 1));

    // rope q at pos MODEL_CTX-1
    const float* qb = q + (size_t)b * (NUM_KV_HEADS * HEAD_DIM) + h * HEAD_DIM;
    const float q1a = qb[2 * sl],      q1b = qb[2 * sl + 1];
    const float q2a = qb[64 + 2 * sl], q2b = qb[65 + 2 * sl];
    float sq0, cq0, sq1, cq1;
    sincosf((float)(MODEL_CTX - 1) * invf0, &sq0, &cq0);
    sincosf((float)(MODEL_CTX - 1) * invf1, &sq1, &cq1);
    const float qr1a = q1a * cq0 - q2a * sq0;
    const float qr1b = q1b * cq1 - q2b * sq1;
    const float qr2a = q2a * cq0 + q1a * sq0;
    const float qr2b = q2b * cq1 + q1b * sq1;

    const int t0 = chunk * CHUNK;
    const size_t head_off = (size_t)h * HEAD_DIM;
    const float scale = 0.08838834764831845f;   // 1/sqrt(128)

    // ---- pass 1: scores ----
    for (int i = hw; i < CHUNK; i += 8) {
        const int t = t0 + i;
        float score;
        if (t < T) {
            const float* kp;
            float posf;
            if (t == T - 1) {
                kp = knew + (size_t)b * (NUM_KV_HEADS * HEAD_DIM) + head_off;
                posf = (float)(MODEL_CTX - 1);
            } else {
                const int blk = btab[b * nbps + (t >> 4)];
                kp = kcache + ((size_t)blk * BLOCK_SZ + (t & 15)) * (NUM_KV_HEADS * HEAD_DIM) + head_off;
                posf = (float)t;
            }
            const float k1a = kp[2 * sl],      k1b = kp[2 * sl + 1];
            const float k2a = kp[64 + 2 * sl], k2b = kp[65 + 2 * sl];
            float s0, c0, s1, c1;
            sincosf(posf * invf0, &s0, &c0);
            sincosf(posf * invf1, &s1, &c1);
            const float r1a = k1a * c0 - k2a * s0;
            const float r1b = k1b * c1 - k2b * s1;
            const float r2a = k2a * c0 + k1a * s0;
            const float r2b = k2b * c1 + k1b * s1;
            float d = r1a * qr1a + r1b * qr1b + r2a * qr2a + r2b * qr2b;
            #pragma unroll
            for (int off = 1; off < 32; off <<= 1) d += __shfl_xor(d, off, 64);
            score = d * scale;
        } else {
            score = -INFINITY;
        }
        if (sl == 0) sc[i] = score;
    }
    __syncthreads();

    // ---- chunk softmax: max, exp, sum ----
    const float sv = sc[tid];
    float m = sv;
    #pragma unroll
    for (int off = 1; off < 64; off <<= 1) m = fmaxf(m, __shfl_xor(m, off, 64));
    if (lane == 0) red[wave] = m;
    __syncthreads();
    m = fmaxf(fmaxf(red[0], red[1]), fmaxf(red[2], red[3]));

    const float p = expf(sv - m);        // -inf slots -> 0
    sc[tid] = p;                          // own slot only; read after next barrier
    float ls = p;
    #pragma unroll
    for (int off = 1; off < 64; off <<= 1) ls += __shfl_xor(ls, off, 64);
    if (lane == 0) red[4 + wave] = ls;    // disjoint from red[0..3] being read
    __syncthreads();
    const float l = red[4] + red[5] + red[6] + red[7];

    // ---- pass 2: p * V ----
    float a1a = 0.f, a1b = 0.f, a2a = 0.f, a2b = 0.f;
    for (int i = hw; i < CHUNK; i += 8) {
        const int t = t0 + i;
        if (t >= T) break;
        const float pw = sc[i];
        const float* vp;
        if (t == T - 1) {
            vp = vnew + (size_t)b * (NUM_KV_HEADS * HEAD_DIM) + head_off;
        } else {
            const int blk = btab[b * nbps + (t >> 4)];
            vp = vcache + ((size_t)blk * BLOCK_SZ + (t & 15)) * (NUM_KV_HEADS * HEAD_DIM) + head_off;
        }
        a1a += pw * vp[2 * sl];
        a1b += pw * vp[2 * sl + 1];
        a2a += pw * vp[64 + 2 * sl];
        a2b += pw * vp[65 + 2 * sl];
    }
    po[hw][2 * sl]      = a1a;
    po[hw][2 * sl + 1]  = a1b;
    po[hw][64 + 2 * sl] = a2a;
    po[hw][65 + 2 * sl] = a2b;
    __syncthreads();

    if (tid < HEAD_DIM) {
        float s = 0.f;
        #pragma unroll
        for (int j = 0; j < 8; j++) s += po[j][tid];
        o_part[((size_t)bh * n_chunks + chunk) * HEAD_DIM + tid] = s;
    }
    if (tid == 0) {
        m_part[bh * n_chunks + chunk] = m;
        l_part[bh * n_chunks + chunk] = l;
    }
}

// Kernel 2: combine split-K partials. 64 blocks x 128 threads.
__global__ void attn_combine(const float* __restrict__ o_part,
                             const float* __restrict__ m_part,
                             const float* __restrict__ l_part,
                             float* __restrict__ out,
                             int n_chunks)
{
    const int bh = blockIdx.x;
    const int d  = threadIdx.x;

    float M = -INFINITY;
    for (int c = 0; c < n_chunks; c++) M = fmaxf(M, m_part[bh * n_chunks + c]);
    float L = 0.f, num = 0.f;
    for (int c = 0; c < n_chunks; c++) {
        const float w = expf(m_part[bh * n_chunks + c] - M);
        L   += l_part[bh * n_chunks + c] * w;
        num += w * o_part[((size_t)bh * n_chunks + c) * HEAD_DIM + d];
    }
    out[(size_t)bh * HEAD_DIM + d] = num / L;
}

extern "C" void kernel_launch(void* const* d_in, const int* in_sizes, int n_in,
                              void* d_out, int out_size, void* d_ws, size_t ws_size,
                              hipStream_t stream) {
    const float* q  = (const float*)d_in[0];
    const float* k  = (const float*)d_in[1];
    const float* v  = (const float*)d_in[2];
    const float* kc = (const float*)d_in[3];
    const float* vc = (const float*)d_in[4];
    const int* bt   = (const int*)d_in[5];
    // d_in[6] = positions (unused by the reference)
    const int* slp  = (const int*)d_in[7];

    const int B    = in_sizes[0] / (NUM_KV_HEADS * HEAD_DIM);
    const int nbps = in_sizes[5] / B;                         // 256
    const int n_chunks = (nbps * BLOCK_SZ + CHUNK - 1) / CHUNK; // 16
    const int BH = B * NUM_KV_HEADS;

    float* o_part = (float*)d_ws;
    float* m_part = o_part + (size_t)BH * n_chunks * HEAD_DIM;
    float* l_part = m_part + (size_t)BH * n_chunks;

    dim3 g1(n_chunks, BH);
    attn_partial<<<g1, 256, 0, stream>>>(q, k, v, kc, vc, bt, slp, nbps,
                                         o_part, m_part, l_part, n_chunks);
    attn_combine<<<dim3(BH), HEAD_DIM, 0, stream>>>(o_part, m_part, l_part,
                                                    (float*)d_out, n_chunks);
}

// Round 2
// 301.322 us; speedup vs baseline: 1.0571x; 1.0571x over previous
//
#include <hip/hip_runtime.h>
#include <math.h>

#define NUM_KV_HEADS 8
#define HEAD_DIM 128
#define HD (NUM_KV_HEADS * HEAD_DIM)
#define BLOCK_SZ 16
#define MODEL_CTX 4096
#define CHUNK 128            // tokens per split-K chunk
#define BLKS_PER_CHUNK (CHUNK / BLOCK_SZ)   // 8

// Kernel 0: rope cos/sin table. tab[t][f] = {cos(t*invf_f), sin(t*invf_f)},
// f in [0,64). Layout float2 -> float4 at (t*128 + 4*sl) gives
// {cos(f0),sin(f0),cos(f1),sin(f1)} for f0=2sl, f1=2sl+1.
__global__ void rope_table(float* __restrict__ tab, int ntab) {
    const int idx = blockIdx.x * 256 + threadIdx.x;   // t*64 + f
    if (idx >= ntab * 64) return;
    const int t = idx >> 6;
    const int f = idx & 63;
    // inv_freq = 10000^(-f/64) = exp(-ln(10000) * f / 64)
    const float inv = expf(-9.210340371976184f * (float)f * (1.0f / 64.0f));
    float s, c;
    sincosf((float)t * inv, &s, &c);
    tab[2 * idx]     = c;
    tab[2 * idx + 1] = s;
}

// Kernel 1: per-(chunk, b*h) partial attention, RoPE via table lookup.
// Half-wave (32 lanes) owns 16 consecutive tokens, processed 4 at a time
// with loads batched ahead of compute for memory-level parallelism.
__global__ __launch_bounds__(256, 8)
void attn_partial(const float* __restrict__ q,
                  const float* __restrict__ knew,
                  const float* __restrict__ vnew,
                  const float* __restrict__ kcache,
                  const float* __restrict__ vcache,
                  const int* __restrict__ btab,
                  const int* __restrict__ seqlen_p,
                  const float* __restrict__ tab,
                  int nbps,
                  float* __restrict__ o_part,    // [B*H][n_chunks][128]
                  float* __restrict__ m_part,    // [B*H][n_chunks]
                  float* __restrict__ l_part,    // [B*H][n_chunks]
                  int n_chunks)
{
    const int chunk = blockIdx.x;
    const int bh    = blockIdx.y;
    const int b     = bh / NUM_KV_HEADS;
    const int h     = bh % NUM_KV_HEADS;
    const int tid   = threadIdx.x;
    const int lane  = tid & 63;
    const int wave  = tid >> 6;
    const int sl    = lane & 31;
    const int half  = lane >> 5;
    const int hw    = wave * 2 + half;    // half-wave 0..7

    __shared__ float sc[CHUNK];
    __shared__ float red[8];
    __shared__ int   sblk[BLKS_PER_CHUNK];
    __shared__ float po[8][HEAD_DIM];

    const int seq_len = *seqlen_p;
    const int rem = (seq_len - 1) & (BLOCK_SZ - 1);
    const int T   = (nbps - 1) * BLOCK_SZ + rem + 1;

    if (tid < BLKS_PER_CHUNK)
        sblk[tid] = btab[b * nbps + chunk * BLKS_PER_CHUNK + tid];
    __syncthreads();

    // rope q at pos MODEL_CTX-1 via table
    const float* qb = q + (size_t)b * HD + h * HEAD_DIM;
    const float2 qa  = *(const float2*)(qb + 2 * sl);
    const float2 qb2 = *(const float2*)(qb + 64 + 2 * sl);
    const float4 qcs = *(const float4*)(tab + (size_t)(MODEL_CTX - 1) * 128 + 4 * sl);
    const float qr1a = qa.x * qcs.x - qb2.x * qcs.y;
    const float qr1b = qa.y * qcs.z - qb2.y * qcs.w;
    const float qr2a = qb2.x * qcs.x + qa.x * qcs.y;
    const float qr2b = qb2.y * qcs.z + qa.y * qcs.w;

    const int t0 = chunk * CHUNK;
    const size_t head_off = (size_t)h * HEAD_DIM;
    const float scale = 0.08838834764831845f;   // 1/sqrt(128)

    const int blk = sblk[hw];
    const float* kbase = kcache + (size_t)blk * BLOCK_SZ * HD + head_off;
    const float* vbase = vcache + (size_t)blk * BLOCK_SZ * HD + head_off;
    const float* knb = knew + (size_t)b * HD + head_off;
    const float* vnb = vnew + (size_t)b * HD + head_off;
    const int tbase = t0 + hw * BLOCK_SZ;       // this half-wave's first token

    // ---- pass 1: scores ----
    for (int j4 = 0; j4 < BLOCK_SZ; j4 += 4) {
        float2 ka[4], kb2v[4];
        float4 cs[4];
        int    valid[4];
        #pragma unroll
        for (int u = 0; u < 4; u++) {
            const int j = j4 + u;
            const int t = tbase + j;
            const bool newlike = (t >= T - 1);
            const float* kp = newlike ? knb : (kbase + (size_t)j * HD);
            const int tt = newlike ? (MODEL_CTX - 1) : t;
            ka[u]   = *(const float2*)(kp + 2 * sl);
            kb2v[u] = *(const float2*)(kp + 64 + 2 * sl);
            cs[u]   = *(const float4*)(tab + (size_t)tt * 128 + 4 * sl);
            valid[u] = (t < T);
        }
        #pragma unroll
        for (int u = 0; u < 4; u++) {
            const float r1a = ka[u].x  * cs[u].x - kb2v[u].x * cs[u].y;
            const float r1b = ka[u].y  * cs[u].z - kb2v[u].y * cs[u].w;
            const float r2a = kb2v[u].x * cs[u].x + ka[u].x  * cs[u].y;
            const float r2b = kb2v[u].y * cs[u].z + ka[u].y  * cs[u].w;
            float d = r1a * qr1a + r1b * qr1b + r2a * qr2a + r2b * qr2b;
            #pragma unroll
            for (int off = 1; off < 32; off <<= 1) d += __shfl_xor(d, off, 64);
            const float score = valid[u] ? d * scale : -INFINITY;
            if (sl == 0) sc[j4 + u + hw * BLOCK_SZ] = score;
        }
    }
    __syncthreads();

    // ---- chunk softmax (waves 0,1 cover the 128 scores) ----
    float sv = 0.0f;
    if (wave < 2) {
        sv = sc[tid];
        float mloc = sv;
        #pragma unroll
        for (int off = 1; off < 64; off <<= 1) mloc = fmaxf(mloc, __shfl_xor(mloc, off, 64));
        if (lane == 0) red[wave] = mloc;
    }
    __syncthreads();
    const float m = fmaxf(red[0], red[1]);
    if (wave < 2) {
        const float p = __expf(sv - m);
        sc[tid] = p;
        float ls = p;
        #pragma unroll
        for (int off = 1; off < 64; off <<= 1) ls += __shfl_xor(ls, off, 64);
        if (lane == 0) red[4 + wave] = ls;
    }
    __syncthreads();
    const float l = red[4] + red[5];

    // ---- pass 2: p * V ----
    float a1a = 0.f, a1b = 0.f, a2a = 0.f, a2b = 0.f;
    for (int j4 = 0; j4 < BLOCK_SZ; j4 += 4) {
        float2 va[4], vb2v[4];
        float  pw[4];
        #pragma unroll
        for (int u = 0; u < 4; u++) {
            const int j = j4 + u;
            const int t = tbase + j;
            const float* vp = (t >= T - 1) ? vnb : (vbase + (size_t)j * HD);
            va[u]   = *(const float2*)(vp + 2 * sl);
            vb2v[u] = *(const float2*)(vp + 64 + 2 * sl);
            pw[u]   = sc[hw * BLOCK_SZ + j];    // 0 for invalid tokens
        }
        #pragma unroll
        for (int u = 0; u < 4; u++) {
            a1a += pw[u] * va[u].x;
            a1b += pw[u] * va[u].y;
            a2a += pw[u] * vb2v[u].x;
            a2b += pw[u] * vb2v[u].y;
        }
    }
    po[hw][2 * sl]      = a1a;
    po[hw][2 * sl + 1]  = a1b;
    po[hw][64 + 2 * sl] = a2a;
    po[hw][65 + 2 * sl] = a2b;
    __syncthreads();

    if (tid < HEAD_DIM) {
        float s = 0.f;
        #pragma unroll
        for (int j = 0; j < 8; j++) s += po[j][tid];
        o_part[((size_t)bh * n_chunks + chunk) * HEAD_DIM + tid] = s;
    }
    if (tid == 0) {
        m_part[bh * n_chunks + chunk] = m;
        l_part[bh * n_chunks + chunk] = l;
    }
}

// Kernel 2: combine split-K partials.
__global__ void attn_combine(const float* __restrict__ o_part,
                             const float* __restrict__ m_part,
                             const float* __restrict__ l_part,
                             float* __restrict__ out,
                             int n_chunks)
{
    const int bh = blockIdx.x;
    const int d  = threadIdx.x;

    float M = -INFINITY;
    for (int c = 0; c < n_chunks; c++) M = fmaxf(M, m_part[bh * n_chunks + c]);
    float L = 0.f, num = 0.f;
    for (int c = 0; c < n_chunks; c++) {
        const float w = __expf(m_part[bh * n_chunks + c] - M);
        L   += l_part[bh * n_chunks + c] * w;
        num += w * o_part[((size_t)bh * n_chunks + c) * HEAD_DIM + d];
    }
    out[(size_t)bh * HEAD_DIM + d] = num / L;
}

extern "C" void kernel_launch(void* const* d_in, const int* in_sizes, int n_in,
                              void* d_out, int out_size, void* d_ws, size_t ws_size,
                              hipStream_t stream) {
    const float* q  = (const float*)d_in[0];
    const float* k  = (const float*)d_in[1];
    const float* v  = (const float*)d_in[2];
    const float* kc = (const float*)d_in[3];
    const float* vc = (const float*)d_in[4];
    const int* bt   = (const int*)d_in[5];
    const int* slp  = (const int*)d_in[7];

    const int B    = in_sizes[0] / HD;
    const int nbps = in_sizes[5] / B;                              // 256
    const int n_chunks = (nbps * BLOCK_SZ + CHUNK - 1) / CHUNK;    // 32
    const int BH = B * NUM_KV_HEADS;

    int ntab = nbps * BLOCK_SZ;
    if (ntab < MODEL_CTX) ntab = MODEL_CTX;

    float* tab    = (float*)d_ws;                                   // ntab*64*2 floats
    float* o_part = tab + (size_t)ntab * 128;
    float* m_part = o_part + (size_t)BH * n_chunks * HEAD_DIM;
    float* l_part = m_part + (size_t)BH * n_chunks;

    const int ttotal = ntab * 64;
    rope_table<<<(ttotal + 255) / 256, 256, 0, stream>>>(tab, ntab);

    dim3 g1(n_chunks, BH);
    attn_partial<<<g1, 256, 0, stream>>>(q, k, v, kc, vc, bt, slp, tab, nbps,
                                         o_part, m_part, l_part, n_chunks);
    attn_combine<<<dim3(BH), HEAD_DIM, 0, stream>>>(o_part, m_part, l_part,
                                                    (float*)d_out, n_chunks);
}